// Round 3
// baseline (869.759 us; speedup 1.0000x reference)
//
#include <hip/hip_runtime.h>
#include <hip/hip_bf16.h>
#include <stdint.h>
#include <stddef.h>

typedef __bf16 bf16_t;
typedef __bf16 bf16x8 __attribute__((ext_vector_type(8)));
typedef __bf16 bf16x4 __attribute__((ext_vector_type(4)));
typedef float floatx4 __attribute__((ext_vector_type(4)));

#define D_MODEL 1024
#define SEQ 2048
#define NB 4
#define NH 16
#define DK 64
#define MTOT 8192  // NB*SEQ

// Load 8 consecutive elements as bf16x8, converting from fp32 if needed.
__device__ inline bf16x8 ld8(const float* p) {
  float4 a = *(const float4*)p;
  float4 b = *(const float4*)(p + 4);
  bf16x8 v;
  v[0] = (bf16_t)a.x; v[1] = (bf16_t)a.y; v[2] = (bf16_t)a.z; v[3] = (bf16_t)a.w;
  v[4] = (bf16_t)b.x; v[5] = (bf16_t)b.y; v[6] = (bf16_t)b.z; v[7] = (bf16_t)b.w;
  return v;
}
__device__ inline bf16x8 ld8(const bf16_t* p) { return *(const bf16x8*)p; }

// ---------------- GEMM: C[M,N] = A[M,K] @ W[N,K]^T  (M=8192, N=K=1024) ----
// MODE 0: C row-major bf16. MODE 1: V-transposed bf16 Vt[(b*1024+n)*SEQ + s].
// MODE 2: C row-major fp32 (final output).
#define BM 128
#define BN 128
#define BK 64
#define LDK 72  // padded LDS stride (bf16 elems)

template <int MODE, typename TA, typename TC>
__global__ __launch_bounds__(256) void gemm_bt(const TA* __restrict__ A,
                                               const float* __restrict__ W,
                                               TC* __restrict__ C) {
  __shared__ __align__(16) bf16_t As[BM * LDK];
  __shared__ __align__(16) bf16_t Bs[BN * LDK];
  const int tid = threadIdx.x;
  const int lane = tid & 63;
  const int wave = tid >> 6;
  const int row0 = blockIdx.x * BM;
  const int col0 = blockIdx.y * BN;
  const int wr = (wave >> 1) * 64;
  const int wc = (wave & 1) * 64;
  const int lrow = lane & 15;
  const int quad = lane >> 4;

  floatx4 acc[4][4] = {};

  for (int k0 = 0; k0 < D_MODEL; k0 += BK) {
#pragma unroll
    for (int i = 0; i < 4; i++) {
      int c = tid + i * 256;
      int r = c >> 3;
      int cc = (c & 7) * 8;
      *(bf16x8*)&As[r * LDK + cc] = ld8(&A[(size_t)(row0 + r) * D_MODEL + k0 + cc]);
      *(bf16x8*)&Bs[r * LDK + cc] = ld8(&W[(size_t)(col0 + r) * D_MODEL + k0 + cc]);
    }
    __syncthreads();
#pragma unroll
    for (int kk = 0; kk < BK; kk += 32) {
      bf16x8 af[4], bfr[4];
#pragma unroll
      for (int i = 0; i < 4; i++)
        af[i] = *(const bf16x8*)&As[(wr + i * 16 + lrow) * LDK + kk + quad * 8];
#pragma unroll
      for (int j = 0; j < 4; j++)
        bfr[j] = *(const bf16x8*)&Bs[(wc + j * 16 + lrow) * LDK + kk + quad * 8];
#pragma unroll
      for (int i = 0; i < 4; i++)
#pragma unroll
        for (int j = 0; j < 4; j++)
          acc[i][j] = __builtin_amdgcn_mfma_f32_16x16x32_bf16(af[i], bfr[j],
                                                              acc[i][j], 0, 0, 0);
    }
    __syncthreads();
  }

  // Epilogue. C/D layout: col = lane&15, row = quad*4 + reg (m89-verified).
#pragma unroll
  for (int i = 0; i < 4; i++) {
#pragma unroll
    for (int j = 0; j < 4; j++) {
      int gr0 = row0 + wr + i * 16 + quad * 4;
      int gc = col0 + wc + j * 16 + lrow;
      if (MODE == 1) {
        int b = gr0 >> 11;       // batch
        int s = gr0 & (SEQ - 1); // seq position (4 consecutive, 4-aligned)
        bf16x4 v;
#pragma unroll
        for (int r = 0; r < 4; r++) v[r] = (bf16_t)acc[i][j][r];
        *(bf16x4*)&C[((size_t)(b * D_MODEL + gc)) * SEQ + s] = v;
      } else {
#pragma unroll
        for (int r = 0; r < 4; r++)
          C[(size_t)(gr0 + r) * D_MODEL + gc] = (TC)acc[i][j][r];
      }
    }
  }
}

// ---------------- Flash attention -----------------------------------------
// Q,K bf16 [B,S,H*dk]; Vt bf16 [B,H,dk,S]; X bf16 [B,S,H*dk]; mask int32.
#define LQ 72   // K LDS stride
#define LV 136  // Vt / P LDS stride
#define LOG2E 1.44269504f

__global__ __launch_bounds__(256) void attn_kernel(
    const bf16_t* __restrict__ Q, const bf16_t* __restrict__ K,
    const bf16_t* __restrict__ Vt, const int* __restrict__ mask,
    bf16_t* __restrict__ X) {
  __shared__ __align__(16) bf16_t Ps[128 * LV];
  __shared__ __align__(16) bf16_t Ks[128 * LQ];
  __shared__ __align__(16) bf16_t Vs[DK * LV];

  const int tid = threadIdx.x;
  const int lane = tid & 63;
  const int wave = tid >> 6;
  const int lrow = lane & 15;
  const int quad = lane >> 4;
  const int qbase = blockIdx.x * 128;
  const int bh = blockIdx.y;
  const int b = bh >> 4;
  const int h = bh & 15;

  // Q fragments straight from global (A-operand: A[m=lane&15][k=quad*8+j]).
  bf16x8 qf[2][2];
#pragma unroll
  for (int qi = 0; qi < 2; qi++)
#pragma unroll
    for (int ks = 0; ks < 2; ks++)
      qf[qi][ks] = *(const bf16x8*)&Q[((size_t)(b * SEQ + qbase + wave * 32 +
                                                qi * 16 + lrow)) *
                                          D_MODEL +
                                      h * DK + ks * 32 + quad * 8];

  floatx4 O[2][4] = {};
  float m_i[2][4], l_i[2][4];
#pragma unroll
  for (int qi = 0; qi < 2; qi++)
#pragma unroll
    for (int r = 0; r < 4; r++) {
      m_i[qi][r] = -1e30f;
      l_i[qi][r] = 0.f;
    }

  for (int kt = 0; kt < SEQ / 128; kt++) {
    const int kbase = kt * 128;
    __syncthreads();  // prev iter's Ks/Vs/Ps reads done before restaging
    // Stage K tile [128 keys x 64 dk]
#pragma unroll
    for (int i = 0; i < 4; i++) {
      int c = tid + i * 256;
      int r = c >> 3;
      int cc = (c & 7) * 8;
      *(bf16x8*)&Ks[r * LQ + cc] =
          *(const bf16x8*)&K[((size_t)(b * SEQ + kbase + r)) * D_MODEL +
                             h * DK + cc];
    }
    // Stage Vt tile [64 d x 128 keys] — pre-transposed in global
#pragma unroll
    for (int i = 0; i < 4; i++) {
      int c = tid + i * 256;
      int d = c >> 4;
      int cc = (c & 15) * 8;
      *(bf16x8*)&Vs[d * LV + cc] =
          *(const bf16x8*)&Vt[((size_t)(b * D_MODEL + h * DK + d)) * SEQ +
                              kbase + cc];
    }
    __syncthreads();

    // S = Q @ K^T. Wave covers 32 q x 128 k.
    floatx4 s[2][8] = {};
#pragma unroll
    for (int kj = 0; kj < 8; kj++) {
#pragma unroll
      for (int ks = 0; ks < 2; ks++) {
        bf16x8 kf =
            *(const bf16x8*)&Ks[(kj * 16 + lrow) * LQ + ks * 32 + quad * 8];
#pragma unroll
        for (int qi = 0; qi < 2; qi++)
          s[qi][kj] = __builtin_amdgcn_mfma_f32_16x16x32_bf16(qf[qi][ks], kf,
                                                              s[qi][kj], 0, 0, 0);
      }
    }

    // Scale + mask + online softmax + write P (bf16) to LDS (C-layout rows)
#pragma unroll
    for (int qi = 0; qi < 2; qi++) {
#pragma unroll
      for (int r = 0; r < 4; r++) {
        int qrow = qbase + wave * 32 + qi * 16 + quad * 4 + r;
        const int* mrow = &mask[((size_t)b * SEQ + qrow) * SEQ + kbase + lrow];
        float mx = -1e30f;
#pragma unroll
        for (int kj = 0; kj < 8; kj++) {
          float sv = s[qi][kj][r] * 0.125f;  // 1/sqrt(dk), exact in fp32
          sv = (mrow[kj * 16] != 0) ? sv : -1e9f;
          s[qi][kj][r] = sv;
          mx = fmaxf(mx, sv);
        }
        mx = fmaxf(mx, __shfl_xor(mx, 1));
        mx = fmaxf(mx, __shfl_xor(mx, 2));
        mx = fmaxf(mx, __shfl_xor(mx, 4));
        mx = fmaxf(mx, __shfl_xor(mx, 8));
        float m_new = fmaxf(m_i[qi][r], mx);
        float alpha = exp2f(fminf(0.f, (m_i[qi][r] - m_new) * LOG2E));
        m_i[qi][r] = m_new;
        float ls = 0.f;
#pragma unroll
        for (int kj = 0; kj < 8; kj++) {
          float p = exp2f(fminf(0.f, (s[qi][kj][r] - m_new) * LOG2E));
          s[qi][kj][r] = p;
          ls += p;
        }
        ls += __shfl_xor(ls, 1);
        ls += __shfl_xor(ls, 2);
        ls += __shfl_xor(ls, 4);
        ls += __shfl_xor(ls, 8);
        l_i[qi][r] = l_i[qi][r] * alpha + ls;
#pragma unroll
        for (int dj = 0; dj < 4; dj++) O[qi][dj][r] *= alpha;
#pragma unroll
        for (int kj = 0; kj < 8; kj++)
          Ps[(wave * 32 + qi * 16 + quad * 4 + r) * LV + kj * 16 + lrow] =
              (bf16_t)s[qi][kj][r];
      }
    }
    __syncthreads();  // P C-layout writes -> A-layout reads (m120 pattern)

    // O += P @ V
#pragma unroll
    for (int ks = 0; ks < 4; ks++) {
      bf16x8 pf[2];
#pragma unroll
      for (int qi = 0; qi < 2; qi++)
        pf[qi] = *(const bf16x8*)&Ps[(wave * 32 + qi * 16 + lrow) * LV +
                                     ks * 32 + quad * 8];
#pragma unroll
      for (int dj = 0; dj < 4; dj++) {
        bf16x8 vf =
            *(const bf16x8*)&Vs[(dj * 16 + lrow) * LV + ks * 32 + quad * 8];
#pragma unroll
        for (int qi = 0; qi < 2; qi++)
          O[qi][dj] = __builtin_amdgcn_mfma_f32_16x16x32_bf16(pf[qi], vf,
                                                              O[qi][dj], 0, 0, 0);
      }
    }
  }

  // Epilogue: X[b, s, h*64 + d] = O / l
#pragma unroll
  for (int qi = 0; qi < 2; qi++) {
#pragma unroll
    for (int r = 0; r < 4; r++) {
      int qrow = qbase + wave * 32 + qi * 16 + quad * 4 + r;
      float li = l_i[qi][r];
      float inv = (li > 0.f) ? 1.f / li : 0.f;
#pragma unroll
      for (int dj = 0; dj < 4; dj++)
        X[((size_t)(b * SEQ + qrow)) * D_MODEL + h * DK + dj * 16 + lrow] =
            (bf16_t)(O[qi][dj][r] * inv);
    }
  }
}

extern "C" void kernel_launch(void* const* d_in, const int* in_sizes, int n_in,
                              void* d_out, int out_size, void* d_ws,
                              size_t ws_size, hipStream_t stream) {
  // Reference dtypes: float32 tensors + int32 mask; output float32.
  const float* query = (const float*)d_in[0];
  const float* key = (const float*)d_in[1];
  const float* value = (const float*)d_in[2];
  const int* mask = (const int*)d_in[3];
  const float* Wq = (const float*)d_in[4];
  const float* Wk = (const float*)d_in[5];
  const float* Wv = (const float*)d_in[6];
  const float* Wo = (const float*)d_in[7];
  float* out = (float*)d_out;

  // Internal bf16 buffers. Qp lives in d_out's first 16 MiB (d_out is 32 MiB
  // fp32; Qp is consumed by attn before the final GEMM overwrites d_out).
  // ws: K (16 MiB) | Vt (16 MiB) | X (16 MiB) = 48 MiB.
  char* ws = (char*)d_ws;
  bf16_t* Qp = (bf16_t*)d_out;
  bf16_t* Kp = (bf16_t*)(ws);
  bf16_t* Vtp = (bf16_t*)(ws + ((size_t)16 << 20));
  bf16_t* Xp = (bf16_t*)(ws + ((size_t)32 << 20));

  dim3 gg(MTOT / BM, D_MODEL / BN);
  gemm_bt<0, float, bf16_t><<<gg, 256, 0, stream>>>(query, Wq, Qp);
  gemm_bt<0, float, bf16_t><<<gg, 256, 0, stream>>>(key, Wk, Kp);
  gemm_bt<1, float, bf16_t><<<gg, 256, 0, stream>>>(value, Wv, Vtp);
  attn_kernel<<<dim3(SEQ / 128, NB * NH), 256, 0, stream>>>(Qp, Kp, Vtp, mask,
                                                            Xp);
  gemm_bt<2, bf16_t, float><<<gg, 256, 0, stream>>>(Xp, Wo, out);
}

// Round 4
// 594.984 us; speedup vs baseline: 1.4618x; 1.4618x over previous
//
#include <hip/hip_runtime.h>
#include <hip/hip_bf16.h>
#include <stdint.h>
#include <stddef.h>

typedef __bf16 bf16_t;
typedef __bf16 bf16x8 __attribute__((ext_vector_type(8)));
typedef __bf16 bf16x4 __attribute__((ext_vector_type(4)));
typedef float floatx4 __attribute__((ext_vector_type(4)));

#define D_MODEL 1024
#define SEQ 2048
#define NB 4
#define NH 16
#define DK 64
#define MTOT 8192  // NB*SEQ

// scale folded into Q projection: 1/sqrt(dk) * log2(e) -> softmax in base 2
#define QSCALE 0.1803368801111204f

__device__ inline bf16x8 ld8f(const float* p) {
  float4 a = *(const float4*)p;
  float4 b = *(const float4*)(p + 4);
  bf16x8 v;
  v[0] = (bf16_t)a.x; v[1] = (bf16_t)a.y; v[2] = (bf16_t)a.z; v[3] = (bf16_t)a.w;
  v[4] = (bf16_t)b.x; v[5] = (bf16_t)b.y; v[6] = (bf16_t)b.z; v[7] = (bf16_t)b.w;
  return v;
}

// async global->LDS, 16B per lane; LDS dest = wave-uniform base + lane*16
typedef const __attribute__((address_space(1))) unsigned int gu32;
typedef __attribute__((address_space(3))) unsigned int lu32;
__device__ static inline void async_copy16(const void* g, void* l) {
  __builtin_amdgcn_global_load_lds((gu32*)g, (lu32*)l, 16, 0, 0);
}

// ---------------- prep: fp32 -> bf16 conversion for q,k,v ----------------
__global__ __launch_bounds__(256) void cvt_kernel(const float* __restrict__ q,
                                                  const float* __restrict__ k,
                                                  const float* __restrict__ v,
                                                  bf16_t* __restrict__ qb,
                                                  bf16_t* __restrict__ kb,
                                                  bf16_t* __restrict__ vb) {
  size_t c = (size_t)blockIdx.x * 256 + threadIdx.x;  // chunk of 8 elems
  const float* src;
  bf16_t* dst;
  size_t off;
  if (c < 1048576) { src = q; dst = qb; off = c; }
  else if (c < 2097152) { src = k; dst = kb; off = c - 1048576; }
  else { src = v; dst = vb; off = c - 2097152; }
  size_t e = off * 8;
  *(bf16x8*)&dst[e] = ld8f(&src[e]);
}

// ---------------- prep: mask int32 -> bitmask (1 bit/key) ----------------
__global__ __launch_bounds__(256) void mask_bits_kernel(
    const int* __restrict__ mask, uint32_t* __restrict__ bits) {
  const int lane = threadIdx.x & 63;
  const size_t w0 = ((size_t)blockIdx.x * blockDim.x + threadIdx.x) >> 6;
  const size_t nw = ((size_t)gridDim.x * blockDim.x) >> 6;
  const size_t total = (size_t)NB * SEQ * SEQ / 64;  // uint64 words
  for (size_t i = w0; i < total; i += nw) {
    int v = mask[i * 64 + lane];
    unsigned long long b = __ballot(v != 0);
    if (lane == 0) *(unsigned long long*)&bits[i * 2] = b;
  }
}

// ---------------- GEMM: C[M,N] = A[M,K](bf16) @ W[N,K](fp32)^T -----------
// MODE 0: C row-major (TC). MODE 1: V-transposed bf16 Vt[(b*1024+n)*SEQ+s].
#define BM 128
#define BN 128
#define BK 64
#define LDB 72  // padded B-side LDS stride

template <int MODE, typename TC>
__global__ __launch_bounds__(256) void gemm_bt(const bf16_t* __restrict__ A,
                                               const float* __restrict__ W,
                                               TC* __restrict__ C, float scale) {
  __shared__ __align__(16) bf16_t As[BM * BK];   // unpadded (global_load_lds)
  __shared__ __align__(16) bf16_t Bs[BN * LDB];  // padded (VGPR staging)
  const int tid = threadIdx.x;
  const int lane = tid & 63;
  const int wave = tid >> 6;
  const int row0 = blockIdx.x * BM;
  const int col0 = blockIdx.y * BN;
  const int wr = (wave >> 1) * 64;
  const int wc = (wave & 1) * 64;
  const int lrow = lane & 15;
  const int quad = lane >> 4;
  const int srow = lane >> 3;        // 0..7 within 8-row group
  const int scol = (lane & 7) * 8;   // elem offset (16B chunks)

  floatx4 acc[4][4] = {};

  for (int k0 = 0; k0 < D_MODEL; k0 += BK) {
    // A-side: async 16B/lane direct to LDS (4 x 1KB segments per wave)
#pragma unroll
    for (int it = 0; it < 4; it++) {
      int r = (wave * 4 + it) * 8 + srow;
      async_copy16(&A[(size_t)(row0 + r) * D_MODEL + k0 + scol],
                   &As[(wave * 4 + it) * 512]);
    }
    // B-side: fp32 -> bf16 through VGPRs
#pragma unroll
    for (int i = 0; i < 4; i++) {
      int c = i * 256 + tid;
      int r = c >> 3;
      int cc = (c & 7) * 8;
      *(bf16x8*)&Bs[r * LDB + cc] = ld8f(&W[(size_t)(col0 + r) * D_MODEL + k0 + cc]);
    }
    __syncthreads();  // drains vmcnt(0): async A copies + B stores visible
#pragma unroll
    for (int kk = 0; kk < BK; kk += 32) {
      bf16x8 af[4], bfr[4];
#pragma unroll
      for (int i = 0; i < 4; i++)
        af[i] = *(const bf16x8*)&As[(wr + i * 16 + lrow) * BK + kk + quad * 8];
#pragma unroll
      for (int j = 0; j < 4; j++)
        bfr[j] = *(const bf16x8*)&Bs[(wc + j * 16 + lrow) * LDB + kk + quad * 8];
#pragma unroll
      for (int i = 0; i < 4; i++)
#pragma unroll
        for (int j = 0; j < 4; j++)
          acc[i][j] = __builtin_amdgcn_mfma_f32_16x16x32_bf16(af[i], bfr[j],
                                                              acc[i][j], 0, 0, 0);
    }
    __syncthreads();
  }

  // Epilogue. C/D layout: col = lane&15, row = quad*4 + reg (m89-verified).
#pragma unroll
  for (int i = 0; i < 4; i++) {
#pragma unroll
    for (int j = 0; j < 4; j++) {
      int gr0 = row0 + wr + i * 16 + quad * 4;
      int gc = col0 + wc + j * 16 + lrow;
      if (MODE == 1) {
        int b = gr0 >> 11;
        int s = gr0 & (SEQ - 1);
        bf16x4 v;
#pragma unroll
        for (int r = 0; r < 4; r++) v[r] = (bf16_t)(acc[i][j][r] * scale);
        *(bf16x4*)&C[((size_t)(b * D_MODEL + gc)) * SEQ + s] = v;
      } else {
#pragma unroll
        for (int r = 0; r < 4; r++)
          C[(size_t)(gr0 + r) * D_MODEL + gc] = (TC)(acc[i][j][r] * scale);
      }
    }
  }
}

// ---------------- Flash attention -----------------------------------------
// Q,K bf16 [B,S,H*dk] (Q pre-scaled by QSCALE); Vt bf16 [B,H,dk,S];
// bits: 1 bit/key, 64 uint32 per (b,q) row. X bf16 [B,S,H*dk].
// q-tile 64, 4 waves; each wave owns 16 q-rows => P round-trip is wave-local.
#define LP 136  // padded stride for Ps / Vs

__global__ __launch_bounds__(256) void attn_kernel(
    const bf16_t* __restrict__ Q, const bf16_t* __restrict__ K,
    const bf16_t* __restrict__ Vt, const uint32_t* __restrict__ bits,
    bf16_t* __restrict__ X) {
  __shared__ __align__(16) bf16_t Ps[64 * LP];   // 17.4 KB (wave-local bands)
  __shared__ __align__(16) bf16_t Ks[128 * DK];  // 16 KB, unpadded (async)
  __shared__ __align__(16) bf16_t Vs[DK * LP];   // 17.4 KB
  const int tid = threadIdx.x;
  const int lane = tid & 63;
  const int wave = tid >> 6;
  const int lrow = lane & 15;
  const int quad = lane >> 4;
  const int qbase = blockIdx.x * 64;
  const int b = blockIdx.y >> 4;
  const int h = blockIdx.y & 15;
  const int q0w = qbase + wave * 16;  // this wave's q-row band

  // Q A-fragments straight from global: A[m=lane&15][k=quad*8+j]
  bf16x8 qf[2];
#pragma unroll
  for (int ks = 0; ks < 2; ks++)
    qf[ks] = *(const bf16x8*)&Q[((size_t)(b * SEQ + q0w + lrow)) * D_MODEL +
                                h * DK + ks * 32 + quad * 8];

  floatx4 O[4] = {};
  float m_i[4], l_i[4];
#pragma unroll
  for (int r = 0; r < 4; r++) { m_i[r] = -1e30f; l_i[r] = 0.f; }

  for (int kt = 0; kt < SEQ / 128; kt++) {
    const int kbase = kt * 128;
    // Prefetch mask bits: 128 bits per owned q-row (rows quad*4+r)
    uint32_t mw[4][4];
#pragma unroll
    for (int r = 0; r < 4; r++)
      *(uint4*)&mw[r][0] =
          *(const uint4*)&bits[((size_t)(b * SEQ + q0w + quad * 4 + r)) * 64 +
                               kt * 4];
    __syncthreads();  // all waves done reading prev Ks/Vs
    // Stage K tile [128 keys x 64 dk] async to LDS
#pragma unroll
    for (int it = 0; it < 4; it++) {
      int r = (wave * 4 + it) * 8 + (lane >> 3);
      async_copy16(&K[((size_t)(b * SEQ + kbase + r)) * D_MODEL + h * DK +
                      (lane & 7) * 8],
                   &Ks[(wave * 4 + it) * 512]);
    }
    // Stage Vt tile [64 d x 128 keys] via VGPRs (padded stride)
#pragma unroll
    for (int i = 0; i < 4; i++) {
      int c = i * 256 + tid;
      int d = c >> 4;
      int cc = (c & 15) * 8;
      *(bf16x8*)&Vs[d * LP + cc] =
          *(const bf16x8*)&Vt[((size_t)(b * D_MODEL + h * DK + d)) * SEQ +
                              kbase + cc];
    }
    __syncthreads();  // drains vmcnt(0) + lgkm: tiles visible to all waves

    // S = Q @ K^T (pre-scaled to log2 units). Wave: 16 q x 128 k.
    floatx4 s[8] = {};
#pragma unroll
    for (int kj = 0; kj < 8; kj++) {
#pragma unroll
      for (int ks = 0; ks < 2; ks++) {
        bf16x8 kf =
            *(const bf16x8*)&Ks[(kj * 16 + lrow) * DK + ks * 32 + quad * 8];
        s[kj] = __builtin_amdgcn_mfma_f32_16x16x32_bf16(qf[ks], kf, s[kj], 0, 0, 0);
      }
    }

    // Mask (bit test) + online softmax (base 2) + P to LDS (wave-local band)
#pragma unroll
    for (int r = 0; r < 4; r++) {
      float mx = -1e30f;
#pragma unroll
      for (int kj = 0; kj < 8; kj++) {
        uint32_t ws = mw[r][kj >> 1] >> lrow;
        uint32_t ok = (kj & 1) ? (ws >> 16) & 1u : ws & 1u;
        float sv = ok ? s[kj][r] : -1e9f;
        s[kj][r] = sv;
        mx = fmaxf(mx, sv);
      }
      mx = fmaxf(mx, __shfl_xor(mx, 1));
      mx = fmaxf(mx, __shfl_xor(mx, 2));
      mx = fmaxf(mx, __shfl_xor(mx, 4));
      mx = fmaxf(mx, __shfl_xor(mx, 8));
      float m_new = fmaxf(m_i[r], mx);
      float alpha = exp2f(m_i[r] - m_new);  // arg <= 0 always
      m_i[r] = m_new;
      float ls = 0.f;
#pragma unroll
      for (int kj = 0; kj < 8; kj++) {
        float p = exp2f(s[kj][r] - m_new);  // arg <= 0 always
        s[kj][r] = p;
        ls += p;
      }
      ls += __shfl_xor(ls, 1);
      ls += __shfl_xor(ls, 2);
      ls += __shfl_xor(ls, 4);
      ls += __shfl_xor(ls, 8);
      l_i[r] = l_i[r] * alpha + ls;
#pragma unroll
      for (int dj = 0; dj < 4; dj++) O[dj][r] *= alpha;
#pragma unroll
      for (int kj = 0; kj < 8; kj++)
        Ps[(wave * 16 + quad * 4 + r) * LP + kj * 16 + lrow] = (bf16_t)s[kj][r];
    }
    // Wave-local RAW fence: this wave reads only the band it just wrote.
    asm volatile("s_waitcnt lgkmcnt(0)" ::: "memory");

    // O += P @ V
#pragma unroll
    for (int ks = 0; ks < 4; ks++) {
      bf16x8 pf =
          *(const bf16x8*)&Ps[(wave * 16 + lrow) * LP + ks * 32 + quad * 8];
#pragma unroll
      for (int dj = 0; dj < 4; dj++) {
        bf16x8 vf =
            *(const bf16x8*)&Vs[(dj * 16 + lrow) * LP + ks * 32 + quad * 8];
        O[dj] = __builtin_amdgcn_mfma_f32_16x16x32_bf16(pf, vf, O[dj], 0, 0, 0);
      }
    }
  }

  // Epilogue: X[b, q, h*64 + d] = O / l
#pragma unroll
  for (int r = 0; r < 4; r++) {
    int qrow = q0w + quad * 4 + r;
    float li = l_i[r];
    float inv = (li > 0.f) ? 1.f / li : 0.f;
#pragma unroll
    for (int dj = 0; dj < 4; dj++)
      X[((size_t)(b * SEQ + qrow)) * D_MODEL + h * DK + dj * 16 + lrow] =
          (bf16_t)(O[dj][r] * inv);
  }
}

extern "C" void kernel_launch(void* const* d_in, const int* in_sizes, int n_in,
                              void* d_out, int out_size, void* d_ws,
                              size_t ws_size, hipStream_t stream) {
  const float* query = (const float*)d_in[0];
  const float* key = (const float*)d_in[1];
  const float* value = (const float*)d_in[2];
  const int* mask = (const int*)d_in[3];
  const float* Wq = (const float*)d_in[4];
  const float* Wk = (const float*)d_in[5];
  const float* Wv = (const float*)d_in[6];
  const float* Wo = (const float*)d_in[7];
  float* out = (float*)d_out;

  // ws (48 MiB, lifetimes disjoint):
  //   [0,16M):  qb (stages 1-2)  -> Kp  (stages 3-5)
  //   [16,32M): kb (stages 1-3)  -> Vtp (stages 4-5)
  //   [32,48M): vb (stages 1-4)  -> Xp  (stages 5-6)
  // d_out (32 MiB fp32): Qp bf16 [0,16M), bits [16M,18M) — both dead before
  // the final GEMM overwrites d_out.
  char* ws = (char*)d_ws;
  bf16_t* qb = (bf16_t*)(ws);
  bf16_t* kb = (bf16_t*)(ws + ((size_t)16 << 20));
  bf16_t* vb = (bf16_t*)(ws + ((size_t)32 << 20));
  bf16_t* Kp = qb;
  bf16_t* Vtp = kb;
  bf16_t* Xp = vb;
  bf16_t* Qp = (bf16_t*)d_out;
  uint32_t* bits = (uint32_t*)((char*)d_out + ((size_t)16 << 20));

  cvt_kernel<<<12288, 256, 0, stream>>>(query, key, value, qb, kb, vb);
  mask_bits_kernel<<<2048, 256, 0, stream>>>(mask, bits);

  dim3 gg(MTOT / BM, D_MODEL / BN);
  gemm_bt<0, bf16_t><<<gg, 256, 0, stream>>>(qb, Wq, Qp, QSCALE);
  gemm_bt<0, bf16_t><<<gg, 256, 0, stream>>>(kb, Wk, Kp, 1.0f);
  gemm_bt<1, bf16_t><<<gg, 256, 0, stream>>>(vb, Wv, Vtp, 1.0f);
  attn_kernel<<<dim3(SEQ / 64, NB * NH), 256, 0, stream>>>(Qp, Kp, Vtp, bits,
                                                           Xp);
  gemm_bt<0, float><<<gg, 256, 0, stream>>>(Xp, Wo, out, 1.0f);
}

// Round 5
// 526.262 us; speedup vs baseline: 1.6527x; 1.1306x over previous
//
#include <hip/hip_runtime.h>
#include <hip/hip_bf16.h>
#include <stdint.h>
#include <stddef.h>

typedef __bf16 bf16_t;
typedef __bf16 bf16x8 __attribute__((ext_vector_type(8)));
typedef __bf16 bf16x4 __attribute__((ext_vector_type(4)));
typedef float floatx4 __attribute__((ext_vector_type(4)));

#define D_MODEL 1024
#define SEQ 2048
#define NB 4
#define NH 16
#define DK 64
#define MTOT 8192  // NB*SEQ

// scale folded into Q projection: 1/sqrt(dk) * log2(e) -> softmax in base 2
#define QSCALE 0.1803368801111204f
// fixed softmax reference point (log2 units): scores ~N(0,1.44), max < 14
#define FMAX 14.0f

__device__ inline bf16x8 ld8f(const float* p) {
  float4 a = *(const float4*)p;
  float4 b = *(const float4*)(p + 4);
  bf16x8 v;
  v[0] = (bf16_t)a.x; v[1] = (bf16_t)a.y; v[2] = (bf16_t)a.z; v[3] = (bf16_t)a.w;
  v[4] = (bf16_t)b.x; v[5] = (bf16_t)b.y; v[6] = (bf16_t)b.z; v[7] = (bf16_t)b.w;
  return v;
}

// async global->LDS, 16B per lane; LDS dest = wave-uniform base + lane*16
typedef const __attribute__((address_space(1))) unsigned int gu32;
typedef __attribute__((address_space(3))) unsigned int lu32;
__device__ static inline void async_copy16(const void* g, void* l) {
  __builtin_amdgcn_global_load_lds((gu32*)g, (lu32*)l, 16, 0, 0);
}

// ---------------- prep: fp32 -> bf16 for q,k,v and Wq,Wk,Wv ---------------
__global__ __launch_bounds__(256) void cvt_kernel(
    const float* __restrict__ q, const float* __restrict__ k,
    const float* __restrict__ v, const float* __restrict__ Wq,
    const float* __restrict__ Wk, const float* __restrict__ Wv,
    bf16_t* __restrict__ qb, bf16_t* __restrict__ kb, bf16_t* __restrict__ vb,
    bf16_t* __restrict__ wqb, bf16_t* __restrict__ wkb,
    bf16_t* __restrict__ wvb) {
  size_t c = (size_t)blockIdx.x * 256 + threadIdx.x;  // chunk of 8 elems
  const float* src;
  bf16_t* dst;
  size_t off;
  if (c < 1048576) { src = q; dst = qb; off = c; }
  else if (c < 2097152) { src = k; dst = kb; off = c - 1048576; }
  else if (c < 3145728) { src = v; dst = vb; off = c - 2097152; }
  else if (c < 3276800) { src = Wq; dst = wqb; off = c - 3145728; }
  else if (c < 3407872) { src = Wk; dst = wkb; off = c - 3276800; }
  else { src = Wv; dst = wvb; off = c - 3407872; }
  size_t e = off * 8;
  *(bf16x8*)&dst[e] = ld8f(&src[e]);
}

// Wo fp32 -> bf16 (runs after attn, into the then-dead Kp slot)
__global__ __launch_bounds__(256) void cvt_w_kernel(const float* __restrict__ W,
                                                    bf16_t* __restrict__ wb) {
  size_t e = ((size_t)blockIdx.x * 256 + threadIdx.x) * 8;
  *(bf16x8*)&wb[e] = ld8f(&W[e]);
}

// ---------------- prep: mask int32 -> bitmask (1 bit/key) ----------------
__global__ __launch_bounds__(256) void mask_bits_kernel(
    const int* __restrict__ mask, uint32_t* __restrict__ bits) {
  const int lane = threadIdx.x & 63;
  const size_t w0 = ((size_t)blockIdx.x * blockDim.x + threadIdx.x) >> 6;
  const size_t nw = ((size_t)gridDim.x * blockDim.x) >> 6;
  const size_t total = (size_t)NB * SEQ * SEQ / 64;  // uint64 words
  for (size_t i = w0; i < total; i += nw) {
    int v = mask[i * 64 + lane];
    unsigned long long b = __ballot(v != 0);
    if (lane == 0) *(unsigned long long*)&bits[i * 2] = b;
  }
}

// ---------------- GEMM: C[M,N] = A[M,K](bf16) @ W[N,K](bf16)^T -----------
// Both tiles async global_load_lds, unpadded, XOR chunk-swizzle:
// LDS[r][chunk c] = G[r][c ^ (r&7)]  (chunk = 16B = 8 bf16).
// MODE 0: C row-major (TC). MODE 1: V-transposed bf16 Vt[(b*1024+n)*SEQ+s].
#define BM 128
#define BN 128
#define BK 64

template <int MODE, typename TC>
__global__ __launch_bounds__(256) void gemm_bt(const bf16_t* __restrict__ A,
                                               const bf16_t* __restrict__ W,
                                               TC* __restrict__ C, float scale) {
  __shared__ __align__(16) bf16_t As[BM * BK];
  __shared__ __align__(16) bf16_t Bs[BN * BK];
  const int tid = threadIdx.x;
  const int lane = tid & 63;
  const int wave = tid >> 6;
  const int row0 = blockIdx.x * BM;
  const int col0 = blockIdx.y * BN;
  const int wr = (wave >> 1) * 64;
  const int wc = (wave & 1) * 64;
  const int lrow = lane & 15;
  const int quad = lane >> 4;
  const int srow = lane >> 3;                  // 0..7 row within segment
  const int scol = ((lane & 7) ^ srow) * 8;    // XOR-swizzled source chunk

  floatx4 acc[4][4] = {};

  for (int k0 = 0; k0 < D_MODEL; k0 += BK) {
#pragma unroll
    for (int it = 0; it < 4; it++) {
      int seg = wave * 4 + it;  // 8-row segment
      async_copy16(&A[(size_t)(row0 + seg * 8 + srow) * D_MODEL + k0 + scol],
                   &As[seg * 512]);
      async_copy16(&W[(size_t)(col0 + seg * 8 + srow) * D_MODEL + k0 + scol],
                   &Bs[seg * 512]);
    }
    __syncthreads();  // drains vmcnt(0): async copies visible
#pragma unroll
    for (int kk = 0; kk < BK; kk += 32) {
      bf16x8 af[4], bfr[4];
#pragma unroll
      for (int i = 0; i < 4; i++)
        af[i] = *(const bf16x8*)&As[(wr + i * 16 + lrow) * BK +
                                    (((kk >> 3) + quad) ^ (lane & 7)) * 8];
#pragma unroll
      for (int j = 0; j < 4; j++)
        bfr[j] = *(const bf16x8*)&Bs[(wc + j * 16 + lrow) * BK +
                                     (((kk >> 3) + quad) ^ (lane & 7)) * 8];
#pragma unroll
      for (int i = 0; i < 4; i++)
#pragma unroll
        for (int j = 0; j < 4; j++)
          acc[i][j] = __builtin_amdgcn_mfma_f32_16x16x32_bf16(af[i], bfr[j],
                                                              acc[i][j], 0, 0, 0);
    }
    __syncthreads();
  }

  // Epilogue. C/D layout: col = lane&15, row = quad*4 + reg (m89-verified).
#pragma unroll
  for (int i = 0; i < 4; i++) {
#pragma unroll
    for (int j = 0; j < 4; j++) {
      int gr0 = row0 + wr + i * 16 + quad * 4;
      int gc = col0 + wc + j * 16 + lrow;
      if (MODE == 1) {
        int b = gr0 >> 11;
        int s = gr0 & (SEQ - 1);
        bf16x4 v;
#pragma unroll
        for (int r = 0; r < 4; r++) v[r] = (bf16_t)(acc[i][j][r] * scale);
        *(bf16x4*)&C[((size_t)(b * D_MODEL + gc)) * SEQ + s] = v;
      } else {
#pragma unroll
        for (int r = 0; r < 4; r++)
          C[(size_t)(gr0 + r) * D_MODEL + gc] = (TC)(acc[i][j][r] * scale);
      }
    }
  }
}

// ---------------- Flash attention -----------------------------------------
// Q,K bf16 [B,S,H*dk] (Q pre-scaled by QSCALE -> scores in log2 units);
// Vt bf16 [B,H,dk,S]; bits 1 bit/key; X bf16 [B,S,H*dk].
// Fixed-max softmax: p = exp2(s - FMAX); masked s=-1e9 -> exp2 -> +0 exactly.
// l accumulated via ones-fragment MFMA fused into the PV loop.
#define LQ 72   // padded K stride (conflict-free b128 reads)
#define LP 136  // padded Ps / Vs stride

__global__ __launch_bounds__(256) void attn_kernel(
    const bf16_t* __restrict__ Q, const bf16_t* __restrict__ K,
    const bf16_t* __restrict__ Vt, const uint32_t* __restrict__ bits,
    bf16_t* __restrict__ X) {
  __shared__ __align__(16) bf16_t Ps[64 * LP];   // wave-local bands
  __shared__ __align__(16) bf16_t Ks[128 * LQ];
  __shared__ __align__(16) bf16_t Vs[DK * LP];
  const int tid = threadIdx.x;
  const int lane = tid & 63;
  const int wave = tid >> 6;
  const int lrow = lane & 15;
  const int quad = lane >> 4;
  const int qbase = blockIdx.x * 64;
  const int b = blockIdx.y >> 4;
  const int h = blockIdx.y & 15;
  const int q0w = qbase + wave * 16;  // this wave's q-row band

  // Q A-fragments straight from global: A[m=lane&15][k=quad*8+j]
  bf16x8 qf[2];
#pragma unroll
  for (int ks = 0; ks < 2; ks++)
    qf[ks] = *(const bf16x8*)&Q[((size_t)(b * SEQ + q0w + lrow)) * D_MODEL +
                                h * DK + ks * 32 + quad * 8];

  bf16x8 ones;
#pragma unroll
  for (int e = 0; e < 8; e++) ones[e] = (bf16_t)1.0f;

  floatx4 O[4] = {};
  floatx4 lsum = {};

  for (int kt = 0; kt < SEQ / 128; kt++) {
    const int kbase = kt * 128;
    // Prefetch mask bits: 128 bits per owned q-row (rows quad*4+r)
    uint32_t mw[4][4];
#pragma unroll
    for (int r = 0; r < 4; r++)
      *(uint4*)&mw[r][0] =
          *(const uint4*)&bits[((size_t)(b * SEQ + q0w + quad * 4 + r)) * 64 +
                               kt * 4];
    __syncthreads();  // all waves done reading prev Ks/Vs
    // Stage K tile [128 keys x 64 dk], padded stride (VGPR path)
#pragma unroll
    for (int i = 0; i < 4; i++) {
      int c = i * 256 + tid;
      int r = c >> 3;
      int cc = (c & 7) * 8;
      *(bf16x8*)&Ks[r * LQ + cc] =
          *(const bf16x8*)&K[((size_t)(b * SEQ + kbase + r)) * D_MODEL +
                             h * DK + cc];
    }
    // Stage Vt tile [64 d x 128 keys], padded stride
#pragma unroll
    for (int i = 0; i < 4; i++) {
      int c = i * 256 + tid;
      int d = c >> 4;
      int cc = (c & 15) * 8;
      *(bf16x8*)&Vs[d * LP + cc] =
          *(const bf16x8*)&Vt[((size_t)(b * D_MODEL + h * DK + d)) * SEQ +
                              kbase + cc];
    }
    __syncthreads();

    // S = Q @ K^T (log2 units). Wave: 16 q x 128 k.
    floatx4 s[8] = {};
#pragma unroll
    for (int kj = 0; kj < 8; kj++) {
#pragma unroll
      for (int ks = 0; ks < 2; ks++) {
        bf16x8 kf =
            *(const bf16x8*)&Ks[(kj * 16 + lrow) * LQ + ks * 32 + quad * 8];
        s[kj] = __builtin_amdgcn_mfma_f32_16x16x32_bf16(qf[ks], kf, s[kj], 0, 0, 0);
      }
    }

    // Fixed-max softmax: p = exp2(s - FMAX); masked -> exp2(-1e9) = +0.
#pragma unroll
    for (int r = 0; r < 4; r++) {
#pragma unroll
      for (int kj = 0; kj < 8; kj++) {
        uint32_t ws = mw[r][kj >> 1] >> lrow;
        uint32_t ok = (kj & 1) ? (ws >> 16) & 1u : ws & 1u;
        float sv = ok ? s[kj][r] : -1e9f;
        float p = exp2f(sv - FMAX);
        Ps[(wave * 16 + quad * 4 + r) * LP + kj * 16 + lrow] = (bf16_t)p;
      }
    }
    // Wave-local RAW fence: this wave reads only the band it just wrote.
    asm volatile("s_waitcnt lgkmcnt(0)" ::: "memory");

    // O += P @ V ; lsum += P @ ones (row-sums of P, fused)
#pragma unroll
    for (int ks = 0; ks < 4; ks++) {
      bf16x8 pf =
          *(const bf16x8*)&Ps[(wave * 16 + lrow) * LP + ks * 32 + quad * 8];
#pragma unroll
      for (int dj = 0; dj < 4; dj++) {
        bf16x8 vf =
            *(const bf16x8*)&Vs[(dj * 16 + lrow) * LP + ks * 32 + quad * 8];
        O[dj] = __builtin_amdgcn_mfma_f32_16x16x32_bf16(pf, vf, O[dj], 0, 0, 0);
      }
      lsum = __builtin_amdgcn_mfma_f32_16x16x32_bf16(pf, ones, lsum, 0, 0, 0);
    }
  }

  // Epilogue: X[b, q, h*64 + d] = O / l
#pragma unroll
  for (int r = 0; r < 4; r++) {
    int qrow = q0w + quad * 4 + r;
    float li = lsum[r];
    float inv = (li > 0.f) ? 1.f / li : 0.f;
#pragma unroll
    for (int dj = 0; dj < 4; dj++)
      X[((size_t)(b * SEQ + qrow)) * D_MODEL + h * DK + dj * 16 + lrow] =
          (bf16_t)(O[dj][r] * inv);
  }
}

extern "C" void kernel_launch(void* const* d_in, const int* in_sizes, int n_in,
                              void* d_out, int out_size, void* d_ws,
                              size_t ws_size, hipStream_t stream) {
  const float* query = (const float*)d_in[0];
  const float* key = (const float*)d_in[1];
  const float* value = (const float*)d_in[2];
  const int* mask = (const int*)d_in[3];
  const float* Wq = (const float*)d_in[4];
  const float* Wk = (const float*)d_in[5];
  const float* Wv = (const float*)d_in[6];
  const float* Wo = (const float*)d_in[7];
  float* out = (float*)d_out;

  // ws (48 MiB, lifetimes disjoint):
  //   [0,16M):  qb (prep..Qgemm)  -> Kp (Kgemm..attn) -> wob [0,2M) (Ogemm)
  //   [16,32M): kb (prep..Kgemm)  -> Vtp (Vgemm..attn)
  //   [32,48M): vb (prep..Vgemm)  -> Xp  (attn..Ogemm)
  // d_out (32 MiB fp32): Qp bf16 [0,16M), bits [16,18M), wqb/wkb/wvb bf16
  // [18,24M) — all dead before the final GEMM overwrites d_out.
  char* ws = (char*)d_ws;
  char* dob = (char*)d_out;
  bf16_t* qb = (bf16_t*)(ws);
  bf16_t* kb = (bf16_t*)(ws + ((size_t)16 << 20));
  bf16_t* vb = (bf16_t*)(ws + ((size_t)32 << 20));
  bf16_t* Kp = qb;
  bf16_t* Vtp = kb;
  bf16_t* Xp = vb;
  bf16_t* wob = (bf16_t*)ws;
  bf16_t* Qp = (bf16_t*)d_out;
  uint32_t* bits = (uint32_t*)(dob + ((size_t)16 << 20));
  bf16_t* wqb = (bf16_t*)(dob + ((size_t)18 << 20));
  bf16_t* wkb = (bf16_t*)(dob + ((size_t)20 << 20));
  bf16_t* wvb = (bf16_t*)(dob + ((size_t)22 << 20));

  cvt_kernel<<<13824, 256, 0, stream>>>(query, key, value, Wq, Wk, Wv, qb, kb,
                                        vb, wqb, wkb, wvb);
  mask_bits_kernel<<<2048, 256, 0, stream>>>(mask, bits);

  dim3 gg(MTOT / BM, D_MODEL / BN);
  gemm_bt<0, bf16_t><<<gg, 256, 0, stream>>>(qb, wqb, Qp, QSCALE);
  gemm_bt<0, bf16_t><<<gg, 256, 0, stream>>>(kb, wkb, Kp, 1.0f);
  gemm_bt<1, bf16_t><<<gg, 256, 0, stream>>>(vb, wvb, Vtp, 1.0f);
  attn_kernel<<<dim3(SEQ / 64, NB * NH), 256, 0, stream>>>(Qp, Kp, Vtp, bits,
                                                           Xp);
  cvt_w_kernel<<<512, 256, 0, stream>>>(Wo, wob);
  gemm_bt<0, float><<<gg, 256, 0, stream>>>(Xp, wob, out, 1.0f);
}

// Round 6
// 451.714 us; speedup vs baseline: 1.9255x; 1.1650x over previous
//
#include <hip/hip_runtime.h>
#include <hip/hip_bf16.h>
#include <stdint.h>
#include <stddef.h>

typedef __bf16 bf16_t;
typedef __bf16 bf16x8 __attribute__((ext_vector_type(8)));
typedef __bf16 bf16x4 __attribute__((ext_vector_type(4)));
typedef float floatx4 __attribute__((ext_vector_type(4)));

#define D_MODEL 1024
#define SEQ 2048
#define NB 4
#define NH 16
#define DK 64
#define MTOT 8192  // NB*SEQ

// scale folded into Q projection: 1/sqrt(dk) * log2(e) -> softmax in base 2
#define QSCALE 0.1803368801111204f
// fixed softmax reference point (log2 units), folded into QK accumulator init
#define FMAX 14.0f

__device__ inline bf16x8 ld8f(const float* p) {
  float4 a = *(const float4*)p;
  float4 b = *(const float4*)(p + 4);
  bf16x8 v;
  v[0] = (bf16_t)a.x; v[1] = (bf16_t)a.y; v[2] = (bf16_t)a.z; v[3] = (bf16_t)a.w;
  v[4] = (bf16_t)b.x; v[5] = (bf16_t)b.y; v[6] = (bf16_t)b.z; v[7] = (bf16_t)b.w;
  return v;
}

// async global->LDS, 16B per lane; LDS dest = wave-uniform base + lane*16
typedef const __attribute__((address_space(1))) unsigned int gu32;
typedef __attribute__((address_space(3))) unsigned int lu32;
__device__ static inline void async_copy16(const void* g, void* l) {
  __builtin_amdgcn_global_load_lds((gu32*)g, (lu32*)l, 16, 0, 0);
}

// ---------------- prep: fp32 -> bf16 for q,k,v and Wq,Wk,Wv ---------------
__global__ __launch_bounds__(256) void cvt_kernel(
    const float* __restrict__ q, const float* __restrict__ k,
    const float* __restrict__ v, const float* __restrict__ Wq,
    const float* __restrict__ Wk, const float* __restrict__ Wv,
    bf16_t* __restrict__ qb, bf16_t* __restrict__ kb, bf16_t* __restrict__ vb,
    bf16_t* __restrict__ wqb, bf16_t* __restrict__ wkb,
    bf16_t* __restrict__ wvb) {
  size_t c = (size_t)blockIdx.x * 256 + threadIdx.x;  // chunk of 8 elems
  const float* src;
  bf16_t* dst;
  size_t off;
  if (c < 1048576) { src = q; dst = qb; off = c; }
  else if (c < 2097152) { src = k; dst = kb; off = c - 1048576; }
  else if (c < 3145728) { src = v; dst = vb; off = c - 2097152; }
  else if (c < 3276800) { src = Wq; dst = wqb; off = c - 3145728; }
  else if (c < 3407872) { src = Wk; dst = wkb; off = c - 3276800; }
  else { src = Wv; dst = wvb; off = c - 3407872; }
  size_t e = off * 8;
  *(bf16x8*)&dst[e] = ld8f(&src[e]);
}

// Wo fp32 -> bf16 (runs after attn, into the then-dead Kp slot)
__global__ __launch_bounds__(256) void cvt_w_kernel(const float* __restrict__ W,
                                                    bf16_t* __restrict__ wb) {
  size_t e = ((size_t)blockIdx.x * 256 + threadIdx.x) * 8;
  *(bf16x8*)&wb[e] = ld8f(&W[e]);
}

// ---------------- prep: mask int32 -> bitmask (1 bit/key) ----------------
__global__ __launch_bounds__(256) void mask_bits_kernel(
    const int* __restrict__ mask, uint32_t* __restrict__ bits) {
  const int lane = threadIdx.x & 63;
  const size_t w0 = ((size_t)blockIdx.x * blockDim.x + threadIdx.x) >> 6;
  const size_t nw = ((size_t)gridDim.x * blockDim.x) >> 6;
  const size_t total = (size_t)NB * SEQ * SEQ / 64;  // uint64 words
  for (size_t i = w0; i < total; i += nw) {
    int v = mask[i * 64 + lane];
    unsigned long long b = __ballot(v != 0);
    if (lane == 0) *(unsigned long long*)&bits[i * 2] = b;
  }
}

// ---------------- GEMM: C[M,N] = A[M,K](bf16) @ W[N,K](bf16)^T -----------
// Both tiles async global_load_lds, unpadded, XOR chunk-swizzle (r5-verified).
// MODE 0: C row-major (TC). MODE 1: V-transposed bf16 Vt[(b*1024+n)*SEQ+s].
#define BM 128
#define BN 128
#define BK 64

template <int MODE, typename TC>
__global__ __launch_bounds__(256) void gemm_bt(const bf16_t* __restrict__ A,
                                               const bf16_t* __restrict__ W,
                                               TC* __restrict__ C, float scale) {
  __shared__ __align__(16) bf16_t As[BM * BK];
  __shared__ __align__(16) bf16_t Bs[BN * BK];
  const int tid = threadIdx.x;
  const int lane = tid & 63;
  const int wave = tid >> 6;
  const int row0 = blockIdx.x * BM;
  const int col0 = blockIdx.y * BN;
  const int wr = (wave >> 1) * 64;
  const int wc = (wave & 1) * 64;
  const int lrow = lane & 15;
  const int quad = lane >> 4;
  const int srow = lane >> 3;                  // 0..7 row within segment
  const int scol = ((lane & 7) ^ srow) * 8;    // XOR-swizzled source chunk

  floatx4 acc[4][4] = {};

  for (int k0 = 0; k0 < D_MODEL; k0 += BK) {
#pragma unroll
    for (int it = 0; it < 4; it++) {
      int seg = wave * 4 + it;  // 8-row segment
      async_copy16(&A[(size_t)(row0 + seg * 8 + srow) * D_MODEL + k0 + scol],
                   &As[seg * 512]);
      async_copy16(&W[(size_t)(col0 + seg * 8 + srow) * D_MODEL + k0 + scol],
                   &Bs[seg * 512]);
    }
    __syncthreads();  // drains vmcnt(0): async copies visible
#pragma unroll
    for (int kk = 0; kk < BK; kk += 32) {
      bf16x8 af[4], bfr[4];
#pragma unroll
      for (int i = 0; i < 4; i++)
        af[i] = *(const bf16x8*)&As[(wr + i * 16 + lrow) * BK +
                                    (((kk >> 3) + quad) ^ (lane & 7)) * 8];
#pragma unroll
      for (int j = 0; j < 4; j++)
        bfr[j] = *(const bf16x8*)&Bs[(wc + j * 16 + lrow) * BK +
                                     (((kk >> 3) + quad) ^ (lane & 7)) * 8];
#pragma unroll
      for (int i = 0; i < 4; i++)
#pragma unroll
        for (int j = 0; j < 4; j++)
          acc[i][j] = __builtin_amdgcn_mfma_f32_16x16x32_bf16(af[i], bfr[j],
                                                              acc[i][j], 0, 0, 0);
    }
    __syncthreads();
  }

  // Epilogue. C/D layout: col = lane&15, row = quad*4 + reg (m89-verified).
#pragma unroll
  for (int i = 0; i < 4; i++) {
#pragma unroll
    for (int j = 0; j < 4; j++) {
      int gr0 = row0 + wr + i * 16 + quad * 4;
      int gc = col0 + wc + j * 16 + lrow;
      if (MODE == 1) {
        int b = gr0 >> 11;
        int s = gr0 & (SEQ - 1);
        bf16x4 v;
#pragma unroll
        for (int r = 0; r < 4; r++) v[r] = (bf16_t)(acc[i][j][r] * scale);
        *(bf16x4*)&C[((size_t)(b * D_MODEL + gc)) * SEQ + s] = v;
      } else {
#pragma unroll
        for (int r = 0; r < 4; r++)
          C[(size_t)(gr0 + r) * D_MODEL + gc] = (TC)(acc[i][j][r] * scale);
      }
    }
  }
}

// ---------------- Flash attention -----------------------------------------
// Q,K bf16 [B,S,H*dk] (Q pre-scaled by QSCALE -> scores in log2 units);
// Vt bf16 [B,H,dk,S]; bits 1 bit/key; X bf16 [B,S,H*dk].
// QK accumulator init = -FMAX (softmax shift for free); p = exp2(s), then
// masked lanes zeroed by cndmask. l via ones-fragment MFMA in the PV loop.
// Ks/Vs: async global_load_lds, unpadded, XOR chunk-swizzle (min-phase b128).
// 1-D grid, bh = blk&63: pins each (b,h) to one XCD's L2 (4 MB working set).
#define LP 136  // padded Ps stride

__global__ __launch_bounds__(256) void attn_kernel(
    const bf16_t* __restrict__ Q, const bf16_t* __restrict__ K,
    const bf16_t* __restrict__ Vt, const uint32_t* __restrict__ bits,
    bf16_t* __restrict__ X) {
  __shared__ __align__(16) bf16_t Ps[64 * LP];    // 17.4 KB, wave-local bands
  __shared__ __align__(16) bf16_t Ks[128 * DK];   // 16 KB, swizzled
  __shared__ __align__(16) bf16_t Vs[DK * 128];   // 16 KB, swizzled
  const int tid = threadIdx.x;
  const int lane = tid & 63;
  const int wave = tid >> 6;
  const int lrow = lane & 15;
  const int quad = lane >> 4;
  const int bh = blockIdx.x & 63;   // XCD-pinned: bh ≡ XCD (mod 8)
  const int qbase = (blockIdx.x >> 6) * 64;
  const int b = bh >> 4;
  const int h = bh & 15;
  const int q0w = qbase + wave * 16;  // this wave's q-row band
  const int srow8 = lane >> 3;                   // K staging: row in 8-row seg
  const int scol8 = ((lane & 7) ^ srow8) * 8;    // K swizzled source chunk
  const int vrow = lane >> 4;                    // V staging: row in 4-row seg

  // Q A-fragments straight from global: A[m=lane&15][k=quad*8+j]
  bf16x8 qf[2];
#pragma unroll
  for (int ks = 0; ks < 2; ks++)
    qf[ks] = *(const bf16x8*)&Q[((size_t)(b * SEQ + q0w + lrow)) * D_MODEL +
                                h * DK + ks * 32 + quad * 8];

  bf16x8 ones;
#pragma unroll
  for (int e = 0; e < 8; e++) ones[e] = (bf16_t)1.0f;

  floatx4 O[4] = {};
  floatx4 lsum = {};

  for (int kt = 0; kt < SEQ / 128; kt++) {
    const int kbase = kt * 128;
    // Prefetch mask bits: 128 bits per owned q-row (rows quad*4+r)
    uint32_t mw[4][4];
#pragma unroll
    for (int r = 0; r < 4; r++)
      *(uint4*)&mw[r][0] =
          *(const uint4*)&bits[((size_t)(b * SEQ + q0w + quad * 4 + r)) * 64 +
                               kt * 4];
    __syncthreads();  // all waves done reading prev Ks/Vs
    // Stage K [128 keys x 64 dk] async, swizzled: LDS(r,c)=G(r, c^(r&7))
#pragma unroll
    for (int it = 0; it < 4; it++) {
      int seg = wave * 4 + it;  // 8-row segment
      async_copy16(&K[((size_t)(b * SEQ + kbase + seg * 8 + srow8)) * D_MODEL +
                      h * DK + scol8],
                   &Ks[seg * 512]);
    }
    // Stage Vt [64 d x 128 keys] async, swizzled: LDS(d,c)=G(d, c^(d&15))
#pragma unroll
    for (int it = 0; it < 4; it++) {
      int seg = wave * 4 + it;  // 4-row segment
      int d = seg * 4 + vrow;
      async_copy16(&Vt[((size_t)(b * D_MODEL + h * DK + d)) * SEQ + kbase +
                       ((lrow ^ (d & 15)) * 8)],
                   &Vs[seg * 512]);
    }
    __syncthreads();  // drains vmcnt(0): async tiles visible

    // S = Q @ K^T - FMAX (bias in acc init). Wave: 16 q x 128 k.
    floatx4 s[8];
#pragma unroll
    for (int kj = 0; kj < 8; kj++) {
      s[kj][0] = -FMAX; s[kj][1] = -FMAX; s[kj][2] = -FMAX; s[kj][3] = -FMAX;
#pragma unroll
      for (int ks = 0; ks < 2; ks++) {
        bf16x8 kf = *(const bf16x8*)&Ks[(kj * 16 + lrow) * DK +
                                        (((4 * ks + quad) ^ (lrow & 7)) * 8)];
        s[kj] = __builtin_amdgcn_mfma_f32_16x16x32_bf16(qf[ks], kf, s[kj], 0, 0, 0);
      }
    }

    // p = exp2(s); masked -> 0 (exact). Write P band to LDS.
#pragma unroll
    for (int r = 0; r < 4; r++) {
#pragma unroll
      for (int kj = 0; kj < 8; kj++) {
        uint32_t ws = mw[r][kj >> 1] >> lrow;
        uint32_t ok = (kj & 1) ? (ws >> 16) & 1u : ws & 1u;
        float p = exp2f(s[kj][r]);
        p = ok ? p : 0.f;
        Ps[(wave * 16 + quad * 4 + r) * LP + kj * 16 + lrow] = (bf16_t)p;
      }
    }
    // Wave-local RAW fence: this wave reads only the band it just wrote.
    asm volatile("s_waitcnt lgkmcnt(0)" ::: "memory");

    // O += P @ V ; lsum += P @ ones (row-sums of P, fused)
#pragma unroll
    for (int ks = 0; ks < 4; ks++) {
      bf16x8 pf =
          *(const bf16x8*)&Ps[(wave * 16 + lrow) * LP + ks * 32 + quad * 8];
#pragma unroll
      for (int dj = 0; dj < 4; dj++) {
        int vr = dj * 16 + lrow;
        bf16x8 vf = *(const bf16x8*)&Vs[vr * 128 +
                                        (((4 * ks + quad) ^ lrow) * 8)];
        O[dj] = __builtin_amdgcn_mfma_f32_16x16x32_bf16(pf, vf, O[dj], 0, 0, 0);
      }
      lsum = __builtin_amdgcn_mfma_f32_16x16x32_bf16(pf, ones, lsum, 0, 0, 0);
    }
  }

  // Epilogue: X[b, q, h*64 + d] = O / l
#pragma unroll
  for (int r = 0; r < 4; r++) {
    int qrow = q0w + quad * 4 + r;
    float li = lsum[r];
    float inv = (li > 0.f) ? 1.f / li : 0.f;
#pragma unroll
    for (int dj = 0; dj < 4; dj++)
      X[((size_t)(b * SEQ + qrow)) * D_MODEL + h * DK + dj * 16 + lrow] =
          (bf16_t)(O[dj][r] * inv);
  }
}

extern "C" void kernel_launch(void* const* d_in, const int* in_sizes, int n_in,
                              void* d_out, int out_size, void* d_ws,
                              size_t ws_size, hipStream_t stream) {
  const float* query = (const float*)d_in[0];
  const float* key = (const float*)d_in[1];
  const float* value = (const float*)d_in[2];
  const int* mask = (const int*)d_in[3];
  const float* Wq = (const float*)d_in[4];
  const float* Wk = (const float*)d_in[5];
  const float* Wv = (const float*)d_in[6];
  const float* Wo = (const float*)d_in[7];
  float* out = (float*)d_out;

  // ws (48 MiB, lifetimes disjoint):
  //   [0,16M):  qb (prep..Qgemm)  -> Kp (Kgemm..attn) -> wob [0,2M) (Ogemm)
  //   [16,32M): kb (prep..Kgemm)  -> Vtp (Vgemm..attn)
  //   [32,48M): vb (prep..Vgemm)  -> Xp  (attn..Ogemm)
  // d_out (32 MiB fp32): Qp bf16 [0,16M), bits [16,18M), wqb/wkb/wvb bf16
  // [18,24M) — all dead before the final GEMM overwrites d_out.
  char* ws = (char*)d_ws;
  char* dob = (char*)d_out;
  bf16_t* qb = (bf16_t*)(ws);
  bf16_t* kb = (bf16_t*)(ws + ((size_t)16 << 20));
  bf16_t* vb = (bf16_t*)(ws + ((size_t)32 << 20));
  bf16_t* Kp = qb;
  bf16_t* Vtp = kb;
  bf16_t* Xp = vb;
  bf16_t* wob = (bf16_t*)ws;
  bf16_t* Qp = (bf16_t*)d_out;
  uint32_t* bits = (uint32_t*)(dob + ((size_t)16 << 20));
  bf16_t* wqb = (bf16_t*)(dob + ((size_t)18 << 20));
  bf16_t* wkb = (bf16_t*)(dob + ((size_t)20 << 20));
  bf16_t* wvb = (bf16_t*)(dob + ((size_t)22 << 20));

  cvt_kernel<<<13824, 256, 0, stream>>>(query, key, value, Wq, Wk, Wv, qb, kb,
                                        vb, wqb, wkb, wvb);
  mask_bits_kernel<<<2048, 256, 0, stream>>>(mask, bits);

  dim3 gg(MTOT / BM, D_MODEL / BN);
  gemm_bt<0, bf16_t><<<gg, 256, 0, stream>>>(qb, wqb, Qp, QSCALE);
  gemm_bt<0, bf16_t><<<gg, 256, 0, stream>>>(kb, wkb, Kp, 1.0f);
  gemm_bt<1, bf16_t><<<gg, 256, 0, stream>>>(vb, wvb, Vtp, 1.0f);
  attn_kernel<<<dim3(SEQ / 64 * NB * NH), 256, 0, stream>>>(Qp, Kp, Vtp, bits,
                                                            Xp);
  cvt_w_kernel<<<512, 256, 0, stream>>>(Wo, wob);
  gemm_bt<0, float><<<gg, 256, 0, stream>>>(Xp, wob, out, 1.0f);
}